// Round 7
// baseline (233.851 us; speedup 1.0000x reference)
//
#include <hip/hip_runtime.h>
#include <hip/hip_bf16.h>
#include <math.h>

typedef __hip_bfloat16 bf16;
typedef __bf16  bf16x8 __attribute__((ext_vector_type(8)));
typedef float   f32x4  __attribute__((ext_vector_type(4)));

#define BB 2
#define NN 2048
#define DD 1024
#define HH 16
#define HD 64
#define LOG2E   1.44269504f
#define SCALE_Q 0.18033688f   /* 0.125 * log2(e), folded into q */

// async global->LDS, 16B/lane; LDS dest = wave-uniform base + lane*16
__device__ __forceinline__ void glds16(const bf16* g, bf16* l) {
    __builtin_amdgcn_global_load_lds((const __attribute__((address_space(1))) void*)g,
                                     (__attribute__((address_space(3))) void*)l, 16, 0, 0);
}
__device__ __forceinline__ unsigned short bfu(float x) {
    bf16 b = __float2bfloat16(x);
    return __builtin_bit_cast(unsigned short, b);
}

// ---------------------------------------------------------------------------
// prep (single launch): [0,2048) cast x -> bf16 ; [2048,2560) bias_perm fp32 ;
// [2560,3328) transpose Wqkv ; [3328,3584) coordproj.
// ---------------------------------------------------------------------------
__global__ __launch_bounds__(256) void prep(const float* __restrict__ x,
                                            const float* __restrict__ bias,
                                            const float* __restrict__ W,
                                            const float* __restrict__ coords,
                                            const float* __restrict__ relw,
                                            bf16* __restrict__ xb,
                                            float* __restrict__ pbf,
                                            bf16* __restrict__ Wt,
                                            bf16* __restrict__ cpn) {
    __shared__ bf16 tsm[64][65];
    const int bid = blockIdx.x, tid = threadIdx.x;
    if (bid < 2048) {
        // cast x (4M elems), 8/thread
        size_t i = ((size_t)bid * 256 + tid) * 8;
        float4 a = *(const float4*)(x + i);
        float4 b = *(const float4*)(x + i + 4);
        bf16 t[8];
        t[0] = __float2bfloat16(a.x); t[1] = __float2bfloat16(a.y);
        t[2] = __float2bfloat16(a.z); t[3] = __float2bfloat16(a.w);
        t[4] = __float2bfloat16(b.x); t[5] = __float2bfloat16(b.y);
        t[6] = __float2bfloat16(b.z); t[7] = __float2bfloat16(b.w);
        *(int4*)(xb + i) = *(int4*)t;
    } else if (bid < 2560) {
        // bias -> permuted fp32 (*log2e), consumption order of attn
        int t    = (bid - 2048) * 256 + tid;     // 0..131071
        int lane = t & 63;
        int wave = (t >> 6) & 3;
        int kt   = (t >> 8) & 31;
        int Qb   = t >> 13;
        int quad = lane >> 4, l15 = lane & 15;
        float v[32];
#pragma unroll
        for (int j = 0; j < 32; ++j) {
            int qb = j >> 4, g = (j >> 2) & 3, r = j & 3;
            int q = Qb * 128 + wave * 32 + qb * 16 + quad * 4 + r;
            int k = kt * 64 + g * 16 + l15;
            v[j] = LOG2E * bias[(size_t)q * NN + k];
        }
        int4* dst = (int4*)(pbf + (size_t)t * 32);
#pragma unroll
        for (int i = 0; i < 8; ++i) dst[i] = ((int4*)v)[i];
    } else if (bid < 3328) {
        // transpose Wqkv (1024x3072) -> Wt (3072x1024) bf16
        int idx = bid - 2560;                    // 0..767
        int n0 = (idx % 48) * 64;
        int k0 = (idx / 48) * 64;
        int tx = tid & 63, tg = tid >> 6;
#pragma unroll
        for (int i = 0; i < 16; ++i) {
            int r = tg + i * 4;
            tsm[r][tx] = __float2bfloat16(W[(size_t)(k0 + r) * 3072 + n0 + tx]);
        }
        __syncthreads();
#pragma unroll
        for (int i = 0; i < 16; ++i) {
            int r = tg + i * 4;
            Wt[(size_t)(n0 + r) * 1024 + k0 + tx] = tsm[tx][r];
        }
    } else {
        // coord_proj, NEGATED, *log2e (+cp[q] cancels in softmax)
        int idx = (bid - 3328) * 256 + tid;      // 0..65535
        int n  = idx & (NN - 1);
        int bh = idx >> 11;
        int h  = bh & (HH - 1);
        int b  = bh >> 4;
        float acc = 0.f;
#pragma unroll
        for (int c = 0; c < 3; ++c)
            acc += coords[(size_t)(b * NN + n) * 3 + c] * relw[h * 3 + c];
        cpn[idx] = __float2bfloat16(-LOG2E * acc);
    }
}

// ---------------------------------------------------------------------------
// qkv GEMM: 128x128 tile, BK=32, glds w=16, swizzle c^=((row>>1)&3).
// R4-style coalesced epilogue: q/k/v all -> (bh,n,d). q pre-scaled.
// ---------------------------------------------------------------------------
__global__ __launch_bounds__(256) void qkv_gemm(const bf16* __restrict__ X,
                                                const bf16* __restrict__ W,
                                                const float* __restrict__ bq,
                                                bf16* __restrict__ qo,
                                                bf16* __restrict__ ko,
                                                bf16* __restrict__ vo) {
    __shared__ __align__(16) bf16 As[128 * 32];
    __shared__ __align__(16) bf16 Bs[128 * 32];
    const int tid  = threadIdx.x;
    const int n0   = blockIdx.x * 128;
    const int m0   = blockIdx.y * 128;
    const int wave = tid >> 6, lane = tid & 63, l15 = lane & 15, quad = lane >> 4;
    const int wm   = wave >> 1, wn = wave & 1;

    f32x4 acc[4][4];
    const f32x4 z4 = {0.f, 0.f, 0.f, 0.f};
#pragma unroll
    for (int i = 0; i < 4; ++i)
#pragma unroll
        for (int j = 0; j < 4; ++j) acc[i][j] = z4;

    for (int kt = 0; kt < 1024; kt += 32) {
        __syncthreads();
#pragma unroll
        for (int j = 0; j < 2; ++j) {
            int s   = (wave * 2 + j) * 64 + lane;       // 0..511
            int row = s >> 2;                           // 0..127
            int c   = (s & 3) ^ ((row >> 1) & 3);       // swizzled col-block
            glds16(X + (size_t)(m0 + row) * 1024 + kt + c * 8, As + (wave * 2 + j) * 512);
            glds16(W + (size_t)(n0 + row) * 1024 + kt + c * 8, Bs + (wave * 2 + j) * 512);
        }
        __syncthreads();

        bf16x8 a[4], b[4];
#pragma unroll
        for (int mt = 0; mt < 4; ++mt) {
            int ra = wm * 64 + mt * 16 + l15;
            a[mt] = *(const bf16x8*)&As[ra * 32 + ((quad ^ ((ra >> 1) & 3)) * 8)];
        }
#pragma unroll
        for (int nt = 0; nt < 4; ++nt) {
            int rb = wn * 64 + nt * 16 + l15;
            b[nt] = *(const bf16x8*)&Bs[rb * 32 + ((quad ^ ((rb >> 1) & 3)) * 8)];
        }
#pragma unroll
        for (int mt = 0; mt < 4; ++mt)
#pragma unroll
            for (int nt = 0; nt < 4; ++nt)
                acc[mt][nt] = __builtin_amdgcn_mfma_f32_16x16x32_bf16(a[mt], b[nt], acc[mt][nt], 0, 0, 0);
    }

    // epilogue: C/D col=lane&15, row=quad*4+reg; all outputs (bh,n,d) coalesced
#pragma unroll
    for (int nt = 0; nt < 4; ++nt) {
        int c    = n0 + wn * 64 + nt * 16 + l15;   // 0..3071, tsel uniform per nt
        int tsel = c >> 10;
        int rem  = c & 1023;
        int h    = rem >> 6, d = rem & 63;
        float bias = bq[c];
        float qs   = (tsel == 0) ? SCALE_Q : 1.0f;
        bf16* outp = (tsel == 0) ? qo : ((tsel == 1) ? ko : vo);
#pragma unroll
        for (int mt = 0; mt < 4; ++mt)
#pragma unroll
            for (int r = 0; r < 4; ++r) {
                int m = m0 + wm * 64 + mt * 16 + quad * 4 + r;   // 0..4095
                int b = m >> 11, n = m & (NN - 1);
                outp[((size_t)(b * HH + h) * NN + n) * HD + d] =
                    __float2bfloat16((acc[mt][nt][r] + bias) * qs);
            }
    }
}

// ---------------------------------------------------------------------------
// transpose V: vw (bh, n, d) -> vt (bh, d, n)
// ---------------------------------------------------------------------------
__global__ __launch_bounds__(256) void transpose_v(const bf16* __restrict__ vw,
                                                   bf16* __restrict__ vt) {
    __shared__ bf16 t[64][65];
    const int bh = blockIdx.y;
    const int n0 = blockIdx.x * 64;
    const size_t base = (size_t)bh * NN * HD;
    const int tx = threadIdx.x & 63, tg = threadIdx.x >> 6;
#pragma unroll
    for (int i = 0; i < 16; ++i) {
        int r = tg + i * 4;
        t[r][tx] = vw[base + (size_t)(n0 + r) * HD + tx];
    }
    __syncthreads();
#pragma unroll
    for (int i = 0; i < 16; ++i) {
        int d = tg + i * 4;
        vt[base + (size_t)d * NN + n0 + tx] = t[tx][d];
    }
}

// ---------------------------------------------------------------------------
// flash attention: 128 q/block, 4 waves x 32 q, static softmax, double-buffered
// K/V glds (one barrier/tile). Bias fp32 from permuted global buffer.
// PsW = single 16-row buffer per wave, qb processed sequentially (in-order DS
// within a wave makes reuse safe). V frags hoisted to registers once per tile.
// LDS 46 KB -> 3 blocks/CU.
// ---------------------------------------------------------------------------
__global__ __launch_bounds__(256, 3) void attn(const bf16* __restrict__ Q,
                                               const bf16* __restrict__ K,
                                               const bf16* __restrict__ Vt_g,
                                               const bf16* __restrict__ cpn_g,
                                               const float* __restrict__ pbf,
                                               float* __restrict__ out) {
    __shared__ __align__(16) bf16 Ks[2][64 * 64];
    __shared__ __align__(16) bf16 Vs[2][64 * 64];      // [d][key]
    __shared__ __align__(16) unsigned PsW[4][16 * 36]; // packed P, per-wave, reused per qb
    __shared__ __align__(16) bf16 cpl[NN];
    const int tid  = threadIdx.x;
    const int Qb   = blockIdx.x;           // 0..15
    const int bh   = blockIdx.y;           // 0..31
    const int b    = bh >> 4, h = bh & 15;
    const int q0   = Qb * 128;
    const int wave = tid >> 6, lane = tid & 63, l15 = lane & 15, quad = lane >> 4;
    const size_t base = (size_t)bh * NN * HD;

    glds16(cpn_g + bh * NN + (wave * 64 + lane) * 8, cpl + wave * 512);

    bf16x8 qf0[2], qf1[2];
#pragma unroll
    for (int qb = 0; qb < 2; ++qb) {
        int qrow = q0 + wave * 32 + qb * 16 + l15;
        qf0[qb] = *(const bf16x8*)&Q[base + (size_t)qrow * HD + quad * 8];
        qf1[qb] = *(const bf16x8*)&Q[base + (size_t)qrow * HD + 32 + quad * 8];
    }

    // prologue: stage tile 0 into buffer 0
#pragma unroll
    for (int j = 0; j < 2; ++j) {
        int ss  = (wave * 2 + j) * 64 + lane;
        int row = ss >> 3;
        int c   = (ss & 7) ^ (row & 7);
        glds16(K    + base + (size_t)row * HD + c * 8,  Ks[0] + (wave * 2 + j) * 512);
        glds16(Vt_g + base + (size_t)row * NN + c * 8,  Vs[0] + (wave * 2 + j) * 512);
    }

    const f32x4 z4 = {0.f, 0.f, 0.f, 0.f};
    float l_loc[2][4];
    f32x4 o[2][4];
#pragma unroll
    for (int qb = 0; qb < 2; ++qb) {
#pragma unroll
        for (int r = 0; r < 4; ++r) l_loc[qb][r] = 0.f;
#pragma unroll
        for (int t = 0; t < 4; ++t) o[qb][t] = z4;
    }

    for (int t = 0; t < 32; ++t) {
        const int cur = t & 1;
        __syncthreads();   // buf[cur] ready; buf[cur^1] free
        if (t < 31) {
            int kk1 = (t + 1) * 64;
#pragma unroll
            for (int j = 0; j < 2; ++j) {
                int ss  = (wave * 2 + j) * 64 + lane;
                int row = ss >> 3;
                int c   = (ss & 7) ^ (row & 7);
                glds16(K    + base + (size_t)(kk1 + row) * HD + c * 8, Ks[cur ^ 1] + (wave * 2 + j) * 512);
                glds16(Vt_g + base + (size_t)row * NN + kk1 + c * 8,   Vs[cur ^ 1] + (wave * 2 + j) * 512);
            }
        }

        // K fragments (shared across both qb)
        bf16x8 k0[4], k1[4];
#pragma unroll
        for (int g = 0; g < 4; ++g) {
            int krow = g * 16 + l15, sw = krow & 7;
            k0[g] = *(const bf16x8*)&Ks[cur][krow * 64 + ((quad ^ sw) * 8)];
            k1[g] = *(const bf16x8*)&Ks[cur][krow * 64 + (((4 + quad) ^ sw) * 8)];
        }

        // QK^T, both qb
        f32x4 s[2][4];
#pragma unroll
        for (int qb = 0; qb < 2; ++qb)
#pragma unroll
            for (int g = 0; g < 4; ++g) {
                s[qb][g] = __builtin_amdgcn_mfma_f32_16x16x32_bf16(qf0[qb], k0[g], z4, 0, 0, 0);
                s[qb][g] = __builtin_amdgcn_mfma_f32_16x16x32_bf16(qf1[qb], k1[g], s[qb][g], 0, 0, 0);
            }

        float mg[4];
#pragma unroll
        for (int g = 0; g < 4; ++g)
            mg[g] = __bfloat162float(cpl[t * 64 + g * 16 + l15]);

        // V fragments hoisted once (register-shared across both qb)
        bf16x8 v0[4], v1[4];
#pragma unroll
        for (int tt = 0; tt < 4; ++tt) {
            int drow = tt * 16 + l15, sw = drow & 7;
            v0[tt] = *(const bf16x8*)&Vs[cur][drow * 64 + ((quad ^ sw) * 8)];
            v1[tt] = *(const bf16x8*)&Vs[cur][drow * 64 + (((4 + quad) ^ sw) * 8)];
        }

        const float* bsrc = pbf + ((((size_t)Qb * 32 + t) * 4 + wave) * 64 + lane) * 32;

#pragma unroll
        for (int qb = 0; qb < 2; ++qb) {
            // bias fp32, 16 values for this qb
            float4 bv[4];
#pragma unroll
            for (int i = 0; i < 4; ++i) bv[i] = ((const float4*)(bsrc + qb * 16))[i];
            const float* bf = (const float*)bv;    // j = g*4 + r

            float p[4][4];
#pragma unroll
            for (int g = 0; g < 4; ++g)
#pragma unroll
                for (int r = 0; r < 4; ++r) {
                    float e = __builtin_amdgcn_exp2f(s[qb][g][r] + bf[g * 4 + r] + mg[g]);
                    p[g][r] = e;
                    l_loc[qb][r] += e;
                }
            // packed P write (8 b32); buffer reuse across qb safe: per-wave DS in-order
#pragma unroll
            for (int g2 = 0; g2 < 2; ++g2)
#pragma unroll
                for (int r = 0; r < 4; ++r) {
                    unsigned pk = (unsigned)bfu(p[g2][r]) | ((unsigned)bfu(p[g2 + 2][r]) << 16);
                    PsW[wave][(quad * 4 + r) * 36 + g2 * 16 + l15] = pk;
                }
            asm volatile("s_waitcnt lgkmcnt(0)" ::: "memory");
            const int4* pr = (const int4*)&PsW[wave][l15 * 36 + quad * 8];
            int4 da = pr[0], db = pr[1];
            union { unsigned u[4]; bf16x8 v; } u0, u1;
            u0.u[0] = __builtin_amdgcn_perm(da.y, da.x, 0x05040100u);
            u0.u[1] = __builtin_amdgcn_perm(da.w, da.z, 0x05040100u);
            u0.u[2] = __builtin_amdgcn_perm(db.y, db.x, 0x05040100u);
            u0.u[3] = __builtin_amdgcn_perm(db.w, db.z, 0x05040100u);
            u1.u[0] = __builtin_amdgcn_perm(da.y, da.x, 0x07060302u);
            u1.u[1] = __builtin_amdgcn_perm(da.w, da.z, 0x07060302u);
            u1.u[2] = __builtin_amdgcn_perm(db.y, db.x, 0x07060302u);
            u1.u[3] = __builtin_amdgcn_perm(db.w, db.z, 0x07060302u);
#pragma unroll
            for (int tt = 0; tt < 4; ++tt) {
                o[qb][tt] = __builtin_amdgcn_mfma_f32_16x16x32_bf16(u0.v, v0[tt], o[qb][tt], 0, 0, 0);
                o[qb][tt] = __builtin_amdgcn_mfma_f32_16x16x32_bf16(u1.v, v1[tt], o[qb][tt], 0, 0, 0);
            }
        }
    }

    // final l reduction + fp32 stores
#pragma unroll
    for (int qb = 0; qb < 2; ++qb)
#pragma unroll
        for (int r = 0; r < 4; ++r) {
#pragma unroll
            for (int d = 1; d < 16; d <<= 1)
                l_loc[qb][r] += __shfl_xor(l_loc[qb][r], d, 64);
            float inv = 1.0f / l_loc[qb][r];
            int qq = q0 + wave * 32 + qb * 16 + quad * 4 + r;
#pragma unroll
            for (int tt = 0; tt < 4; ++tt)
                out[((size_t)(b * NN + qq)) * DD + h * HD + tt * 16 + l15] =
                    o[qb][tt][r] * inv;
        }
}

// ---------------------------------------------------------------------------
extern "C" void kernel_launch(void* const* d_in, const int* in_sizes, int n_in,
                              void* d_out, int out_size, void* d_ws, size_t ws_size,
                              hipStream_t stream) {
    const float* x      = (const float*)d_in[0];
    const float* coords = (const float*)d_in[1];
    const float* abias  = (const float*)d_in[2];
    const float* Wqkv   = (const float*)d_in[3];
    const float* bqkv   = (const float*)d_in[4];
    const float* relw   = (const float*)d_in[5];
    float* out = (float*)d_out;

    char* ws = (char*)d_ws;
    bf16*  xb  = (bf16*)(ws);                      // 8 MB; becomes vt after gemm
    bf16*  vt  = (bf16*)(ws);                      // alias (xb dead after gemm)
    bf16*  qw  = (bf16*)(ws + 8388608);            // 8 MB
    bf16*  kw  = (bf16*)(ws + 16777216);           // 8 MB
    bf16*  vw  = (bf16*)(ws + 25165824);           // 8 MB (bh,n,d)
    bf16*  Wt  = (bf16*)(ws + 33554432);           // 6 MB
    float* pbf = (float*)(ws + 39845888);          // 16 MB permuted bias fp32
    bf16*  cpb = (bf16*)(ws + 56623104);           // 128 KB

    prep       <<<dim3(3584),   256, 0, stream>>>(x, abias, Wqkv, coords, relw,
                                                  xb, pbf, Wt, cpb);
    qkv_gemm   <<<dim3(24, 32), 256, 0, stream>>>(xb, Wt, bqkv, qw, kw, vw);
    transpose_v<<<dim3(32, 32), 256, 0, stream>>>(vw, vt);
    attn       <<<dim3(16, 32), 256, 0, stream>>>(qw, kw, vt, cpb, pbf, out);
}

// Round 8
// 208.559 us; speedup vs baseline: 1.1213x; 1.1213x over previous
//
#include <hip/hip_runtime.h>
#include <hip/hip_bf16.h>
#include <math.h>

typedef __hip_bfloat16 bf16;
typedef __bf16  bf16x8 __attribute__((ext_vector_type(8)));
typedef float   f32x4  __attribute__((ext_vector_type(4)));

#define BB 2
#define NN 2048
#define DD 1024
#define HH 16
#define HD 64
#define LOG2E   1.44269504f
#define SCALE_Q 0.18033688f   /* 0.125 * log2(e), folded into q */

// async global->LDS, 16B/lane; LDS dest = wave-uniform base + lane*16
__device__ __forceinline__ void glds16(const bf16* g, bf16* l) {
    __builtin_amdgcn_global_load_lds((const __attribute__((address_space(1))) void*)g,
                                     (__attribute__((address_space(3))) void*)l, 16, 0, 0);
}
__device__ __forceinline__ unsigned short bfu(float x) {
    bf16 b = __float2bfloat16(x);
    return __builtin_bit_cast(unsigned short, b);
}

// ---------------------------------------------------------------------------
// prep (single launch): [0,2048) cast x ; [2048,3072) bias_perm fp32 (8-wave
// consumption order) ; [3072,3840) transpose Wqkv ; [3840,4096) coordproj.
// ---------------------------------------------------------------------------
__global__ __launch_bounds__(256) void prep(const float* __restrict__ x,
                                            const float* __restrict__ bias,
                                            const float* __restrict__ W,
                                            const float* __restrict__ coords,
                                            const float* __restrict__ relw,
                                            bf16* __restrict__ xb,
                                            float* __restrict__ pbf,
                                            bf16* __restrict__ Wt,
                                            bf16* __restrict__ cpn) {
    __shared__ bf16 tsm[64][65];
    const int bid = blockIdx.x, tid = threadIdx.x;
    if (bid < 2048) {
        size_t i = ((size_t)bid * 256 + tid) * 8;
        float4 a = *(const float4*)(x + i);
        float4 b = *(const float4*)(x + i + 4);
        bf16 t[8];
        t[0] = __float2bfloat16(a.x); t[1] = __float2bfloat16(a.y);
        t[2] = __float2bfloat16(a.z); t[3] = __float2bfloat16(a.w);
        t[4] = __float2bfloat16(b.x); t[5] = __float2bfloat16(b.y);
        t[6] = __float2bfloat16(b.z); t[7] = __float2bfloat16(b.w);
        *(int4*)(xb + i) = *(int4*)t;
    } else if (bid < 3072) {
        // pbf[t*16 + g*4 + r] = log2e*bias[q][k], t = ((Qb*32+kt)*8+wave)*64+lane,
        // q = Qb*128 + wave*16 + quad*4 + r, k = kt*64 + g*16 + l15
        int t    = (bid - 2048) * 256 + tid;     // 0..262143
        int lane = t & 63;
        int wave = (t >> 6) & 7;
        int kt   = (t >> 9) & 31;
        int Qb   = t >> 14;
        int quad = lane >> 4, l15 = lane & 15;
        float v[16];
#pragma unroll
        for (int j = 0; j < 16; ++j) {
            int g = j >> 2, r = j & 3;
            int q = Qb * 128 + wave * 16 + quad * 4 + r;
            int k = kt * 64 + g * 16 + l15;
            v[j] = LOG2E * bias[(size_t)q * NN + k];
        }
        int4* dst = (int4*)(pbf + (size_t)t * 16);
#pragma unroll
        for (int i = 0; i < 4; ++i) dst[i] = ((int4*)v)[i];
    } else if (bid < 3840) {
        int idx = bid - 3072;                    // 0..767
        int n0 = (idx % 48) * 64;
        int k0 = (idx / 48) * 64;
        int tx = tid & 63, tg = tid >> 6;
#pragma unroll
        for (int i = 0; i < 16; ++i) {
            int r = tg + i * 4;
            tsm[r][tx] = __float2bfloat16(W[(size_t)(k0 + r) * 3072 + n0 + tx]);
        }
        __syncthreads();
#pragma unroll
        for (int i = 0; i < 16; ++i) {
            int r = tg + i * 4;
            Wt[(size_t)(n0 + r) * 1024 + k0 + tx] = tsm[tx][r];
        }
    } else {
        int idx = (bid - 3840) * 256 + tid;      // 0..65535
        int n  = idx & (NN - 1);
        int bh = idx >> 11;
        int h  = bh & (HH - 1);
        int b  = bh >> 4;
        float acc = 0.f;
#pragma unroll
        for (int c = 0; c < 3; ++c)
            acc += coords[(size_t)(b * NN + n) * 3 + c] * relw[h * 3 + c];
        cpn[idx] = __float2bfloat16(-LOG2E * acc);
    }
}

// ---------------------------------------------------------------------------
// qkv GEMM: 128x128 tile, BK=32, glds w=16, swizzle c^=((row>>1)&3).
// V written DIRECTLY TRANSPOSED (bh,d,n); q pre-scaled by SCALE_Q. (R6 kernel)
// ---------------------------------------------------------------------------
__global__ __launch_bounds__(256) void qkv_gemm(const bf16* __restrict__ X,
                                                const bf16* __restrict__ W,
                                                const float* __restrict__ bq,
                                                bf16* __restrict__ qo,
                                                bf16* __restrict__ ko,
                                                bf16* __restrict__ vt) {
    __shared__ __align__(16) bf16 As[128 * 32];
    __shared__ __align__(16) bf16 Bs[128 * 32];
    const int tid  = threadIdx.x;
    const int n0   = blockIdx.x * 128;
    const int m0   = blockIdx.y * 128;
    const int wave = tid >> 6, lane = tid & 63, l15 = lane & 15, quad = lane >> 4;
    const int wm   = wave >> 1, wn = wave & 1;

    f32x4 acc[4][4];
    const f32x4 z4 = {0.f, 0.f, 0.f, 0.f};
#pragma unroll
    for (int i = 0; i < 4; ++i)
#pragma unroll
        for (int j = 0; j < 4; ++j) acc[i][j] = z4;

    for (int kt = 0; kt < 1024; kt += 32) {
        __syncthreads();
#pragma unroll
        for (int j = 0; j < 2; ++j) {
            int s   = (wave * 2 + j) * 64 + lane;       // 0..511
            int row = s >> 2;                           // 0..127
            int c   = (s & 3) ^ ((row >> 1) & 3);       // swizzled col-block
            glds16(X + (size_t)(m0 + row) * 1024 + kt + c * 8, As + (wave * 2 + j) * 512);
            glds16(W + (size_t)(n0 + row) * 1024 + kt + c * 8, Bs + (wave * 2 + j) * 512);
        }
        __syncthreads();

        bf16x8 a[4], b[4];
#pragma unroll
        for (int mt = 0; mt < 4; ++mt) {
            int ra = wm * 64 + mt * 16 + l15;
            a[mt] = *(const bf16x8*)&As[ra * 32 + ((quad ^ ((ra >> 1) & 3)) * 8)];
        }
#pragma unroll
        for (int nt = 0; nt < 4; ++nt) {
            int rb = wn * 64 + nt * 16 + l15;
            b[nt] = *(const bf16x8*)&Bs[rb * 32 + ((quad ^ ((rb >> 1) & 3)) * 8)];
        }
#pragma unroll
        for (int mt = 0; mt < 4; ++mt)
#pragma unroll
            for (int nt = 0; nt < 4; ++nt)
                acc[mt][nt] = __builtin_amdgcn_mfma_f32_16x16x32_bf16(a[mt], b[nt], acc[mt][nt], 0, 0, 0);
    }

#pragma unroll
    for (int nt = 0; nt < 4; ++nt) {
        int c    = n0 + wn * 64 + nt * 16 + l15;   // 0..3071, tsel uniform per nt
        int tsel = c >> 10;
        int rem  = c & 1023;
        int h    = rem >> 6, d = rem & 63;
        float bias = bq[c];
        float qs   = (tsel == 0) ? SCALE_Q : 1.0f;
#pragma unroll
        for (int mt = 0; mt < 4; ++mt)
#pragma unroll
            for (int r = 0; r < 4; ++r) {
                int m = m0 + wm * 64 + mt * 16 + quad * 4 + r;   // 0..4095
                int b = m >> 11, n = m & (NN - 1);
                bf16 val = __float2bfloat16((acc[mt][nt][r] + bias) * qs);
                if (tsel == 2)
                    vt[((size_t)(b * HH + h) * HD + d) * NN + n] = val;
                else
                    ((tsel == 1) ? ko : qo)[((size_t)(b * HH + h) * NN + n) * HD + d] = val;
            }
    }
}

// ---------------------------------------------------------------------------
// flash attention: 512 threads = 8 waves x 16 q, 128 q/block, grid 512
// -> 2 blocks/CU x 8 waves = 16 waves/CU (2x R6 occupancy).
// Static softmax, dbuf K/V (one barrier/tile, 1 glds/buf/wave), fp32 permuted
// bias via VMEM, batched PsW write -> one lgkmcnt -> read. LDS 55296 B.
// ---------------------------------------------------------------------------
__global__ __launch_bounds__(512, 4) void attn(const bf16* __restrict__ Q,
                                               const bf16* __restrict__ K,
                                               const bf16* __restrict__ Vt_g,
                                               const bf16* __restrict__ cpn_g,
                                               const float* __restrict__ pbf,
                                               float* __restrict__ out) {
    __shared__ __align__(16) bf16 Ks[2][64 * 64];
    __shared__ __align__(16) bf16 Vs[2][64 * 64];      // [d][key]
    __shared__ __align__(16) unsigned PsW[8][16 * 36]; // packed P, per-wave
    __shared__ __align__(16) bf16 cpl[NN];             // -log2e * cp[bh][*]
    const int tid  = threadIdx.x;
    const int Qb   = blockIdx.x;           // 0..15
    const int bh   = blockIdx.y;           // 0..31
    const int b    = bh >> 4, h = bh & 15;
    const int q0   = Qb * 128;
    const int wave = tid >> 6, lane = tid & 63, l15 = lane & 15, quad = lane >> 4;
    const size_t base = (size_t)bh * NN * HD;

    // stage cp row (4 KB) with waves 0..3 (wave-uniform branch)
    if (wave < 4)
        glds16(cpn_g + bh * NN + (wave * 64 + lane) * 8, cpl + wave * 512);

    // Q fragments: 16 q-rows per wave, in registers for the whole kernel
    const int qrow = q0 + wave * 16 + l15;
    bf16x8 qf0 = *(const bf16x8*)&Q[base + (size_t)qrow * HD + quad * 8];
    bf16x8 qf1 = *(const bf16x8*)&Q[base + (size_t)qrow * HD + 32 + quad * 8];

    // prologue: stage tile 0 into buffer 0 (one glds per buffer per wave)
    {
        int s   = wave * 64 + lane;            // 0..511
        int row = s >> 3;                      // 0..63
        int c   = (s & 7) ^ (row & 7);
        glds16(K    + base + (size_t)row * HD + c * 8, Ks[0] + wave * 512);
        glds16(Vt_g + base + (size_t)row * NN + c * 8, Vs[0] + wave * 512);
    }

    const f32x4 z4 = {0.f, 0.f, 0.f, 0.f};
    float l_loc[4] = {0.f, 0.f, 0.f, 0.f};
    f32x4 o[4];
#pragma unroll
    for (int t = 0; t < 4; ++t) o[t] = z4;

    for (int t = 0; t < 32; ++t) {
        const int cur = t & 1;
        __syncthreads();   // buf[cur] ready (vmcnt drained); buf[cur^1] free
        if (t < 31) {      // prefetch tile t+1
            int kk1 = (t + 1) * 64;
            int s   = wave * 64 + lane;
            int row = s >> 3;
            int c   = (s & 7) ^ (row & 7);
            glds16(K    + base + (size_t)(kk1 + row) * HD + c * 8, Ks[cur ^ 1] + wave * 512);
            glds16(Vt_g + base + (size_t)row * NN + kk1 + c * 8,   Vs[cur ^ 1] + wave * 512);
        }

        // --- QK^T (K frags loaded per g to bound register pressure)
        f32x4 s4[4];
#pragma unroll
        for (int g = 0; g < 4; ++g) {
            int krow = g * 16 + l15, sw = krow & 7;
            bf16x8 k0 = *(const bf16x8*)&Ks[cur][krow * 64 + ((quad ^ sw) * 8)];
            bf16x8 k1 = *(const bf16x8*)&Ks[cur][krow * 64 + (((4 + quad) ^ sw) * 8)];
            s4[g] = __builtin_amdgcn_mfma_f32_16x16x32_bf16(qf0, k0, z4, 0, 0, 0);
            s4[g] = __builtin_amdgcn_mfma_f32_16x16x32_bf16(qf1, k1, s4[g], 0, 0, 0);
        }

        // --- bias (fp32, permuted consumption order) + cp[k]
        float4 bv[4];
        {
            const float* bsrc = pbf + ((((size_t)Qb * 32 + t) * 8 + wave) * 64 + lane) * 16;
#pragma unroll
            for (int i = 0; i < 4; ++i) bv[i] = ((const float4*)bsrc)[i];
        }
        const float* bf = (const float*)bv;    // j = g*4 + r
        float mg[4];
#pragma unroll
        for (int g = 0; g < 4; ++g)
            mg[g] = __bfloat162float(cpl[t * 64 + g * 16 + l15]);

        // --- p = exp2(s + bias' + mg); lane-local l accumulation
        float p[4][4];
#pragma unroll
        for (int g = 0; g < 4; ++g)
#pragma unroll
            for (int r = 0; r < 4; ++r) {
                float e = __builtin_amdgcn_exp2f(s4[g][r] + bf[g * 4 + r] + mg[g]);
                p[g][r] = e;
                l_loc[r] += e;
            }

        // --- packed P write (8 b32), one wait, read back as A-frags
#pragma unroll
        for (int g2 = 0; g2 < 2; ++g2)
#pragma unroll
            for (int r = 0; r < 4; ++r) {
                unsigned pk = (unsigned)bfu(p[g2][r]) | ((unsigned)bfu(p[g2 + 2][r]) << 16);
                PsW[wave][(quad * 4 + r) * 36 + g2 * 16 + l15] = pk;
            }
        asm volatile("s_waitcnt lgkmcnt(0)" ::: "memory");   // wave-private, in-order DS
        const int4* pr = (const int4*)&PsW[wave][l15 * 36 + quad * 8];
        int4 da = pr[0], db = pr[1];
        union { unsigned u[4]; bf16x8 v; } u0, u1;
        u0.u[0] = __builtin_amdgcn_perm(da.y, da.x, 0x05040100u);
        u0.u[1] = __builtin_amdgcn_perm(da.w, da.z, 0x05040100u);
        u0.u[2] = __builtin_amdgcn_perm(db.y, db.x, 0x05040100u);
        u0.u[3] = __builtin_amdgcn_perm(db.w, db.z, 0x05040100u);
        u1.u[0] = __builtin_amdgcn_perm(da.y, da.x, 0x07060302u);
        u1.u[1] = __builtin_amdgcn_perm(da.w, da.z, 0x07060302u);
        u1.u[2] = __builtin_amdgcn_perm(db.y, db.x, 0x07060302u);
        u1.u[3] = __builtin_amdgcn_perm(db.w, db.z, 0x07060302u);

        // --- PV (V frags loaded at use)
#pragma unroll
        for (int tt = 0; tt < 4; ++tt) {
            int drow = tt * 16 + l15, sw = drow & 7;
            bf16x8 v0 = *(const bf16x8*)&Vs[cur][drow * 64 + ((quad ^ sw) * 8)];
            bf16x8 v1 = *(const bf16x8*)&Vs[cur][drow * 64 + (((4 + quad) ^ sw) * 8)];
            o[tt] = __builtin_amdgcn_mfma_f32_16x16x32_bf16(u0.v, v0, o[tt], 0, 0, 0);
            o[tt] = __builtin_amdgcn_mfma_f32_16x16x32_bf16(u1.v, v1, o[tt], 0, 0, 0);
        }
    }

    // final l reduction (16 lanes per quad-row) + fp32 stores
#pragma unroll
    for (int r = 0; r < 4; ++r) {
#pragma unroll
        for (int d = 1; d < 16; d <<= 1)
            l_loc[r] += __shfl_xor(l_loc[r], d, 64);
        float inv = 1.0f / l_loc[r];
        int qq = q0 + wave * 16 + quad * 4 + r;
#pragma unroll
        for (int tt = 0; tt < 4; ++tt)
            out[((size_t)(b * NN + qq)) * DD + h * HD + tt * 16 + l15] =
                o[tt][r] * inv;
    }
}

// ---------------------------------------------------------------------------
extern "C" void kernel_launch(void* const* d_in, const int* in_sizes, int n_in,
                              void* d_out, int out_size, void* d_ws, size_t ws_size,
                              hipStream_t stream) {
    const float* x      = (const float*)d_in[0];
    const float* coords = (const float*)d_in[1];
    const float* abias  = (const float*)d_in[2];
    const float* Wqkv   = (const float*)d_in[3];
    const float* bqkv   = (const float*)d_in[4];
    const float* relw   = (const float*)d_in[5];
    float* out = (float*)d_out;

    char* ws = (char*)d_ws;
    bf16*  xb  = (bf16*)(ws);                      // 8 MB
    bf16*  qw  = (bf16*)(ws + 8388608);            // 8 MB
    bf16*  kw  = (bf16*)(ws + 16777216);           // 8 MB
    bf16*  vt  = (bf16*)(ws + 25165824);           // 8 MB (bh,d,n) via gemm epilogue
    bf16*  Wt  = (bf16*)(ws + 33554432);           // 6 MB
    float* pbf = (float*)(ws + 39845888);          // 16 MB permuted bias fp32
    bf16*  cpb = (bf16*)(ws + 56623104);           // 128 KB

    prep    <<<dim3(4096),   256, 0, stream>>>(x, abias, Wqkv, coords, relw,
                                               xb, pbf, Wt, cpb);
    qkv_gemm<<<dim3(24, 32), 256, 0, stream>>>(xb, Wt, bqkv, qw, kw, vt);
    attn    <<<dim3(16, 32), 512, 0, stream>>>(qw, kw, vt, cpb, pbf, out);
}